// Round 3
// baseline (328.587 us; speedup 1.0000x reference)
//
#include <hip/hip_runtime.h>

// f32 in/out pipeline: MFMA split-bf16 GEMMs + CSR gathers.
// Round 11: (a) persistent GEMM - whole pre-split B resides in LDS (144KB max),
// staged ONCE per block, then barrier-free loop over 128-row tiles (all three
// GEMMs were ~45us regardless of K => per-block stage/barrier fixed cost, now
// amortized). (b) XCD-sliced gathers: intermediates stored plane-major (8 planes
// of 16 or 8 channels); gather blocks pin plane = blockIdx&7 -> per-XCD working
// set 1.6MB < 4MB L2, random reads become L2-local. (c) detect folded into
// bin_scatter, wsplit merged into one launch.

typedef unsigned short u16;
typedef unsigned int   u32;
typedef _Float16 f16;
typedef __attribute__((ext_vector_type(8))) short short8;     // 8 bf16 (4 VGPRs)
typedef __attribute__((ext_vector_type(8))) _Float16 half8;   // 8 f16 (16B)
typedef __attribute__((ext_vector_type(4))) float f32x4;      // MFMA C/D frag

static const int BCAP = 3072;   // tmp capacity per 128-id bucket (mean fill ~2046)

__device__ __forceinline__ float bf2f(u16 u) {
    return __builtin_bit_cast(float, (u32)u << 16);
}
__device__ __forceinline__ u16 f2bf(float f) {
    u32 b = __builtin_bit_cast(u32, f);
    b += 0x7FFFu + ((b >> 16) & 1u);   // RNE (finite)
    return (u16)(b >> 16);
}

// ---------- one-time weight split: W[K,N] f32 -> [K/64][2][N][72] bf16 hi/lo ----------
__device__ __forceinline__ void wsplit_one(const float* __restrict__ W, u16* __restrict__ out,
                                           int K, int N, int local)
{
    int kp = local % 72;
    int rest = local / 72;
    int n = rest % N;
    int c = rest / N;
    float v = 0.f;
    if (kp < 64) v = W[(size_t)(c * 64 + kp) * N + n];
    u16 h = f2bf(v);
    u16 l = f2bf(v - bf2f(h));
    size_t base = (size_t)c * (2 * (size_t)N * 72);
    out[base + (size_t)n * 72 + kp] = h;
    out[base + (size_t)N * 72 + (size_t)n * 72 + kp] = l;
}

__global__ __launch_bounds__(256) void wsplit_all_kernel(
    const float* __restrict__ W1, const float* __restrict__ W2, const float* __restrict__ Wp,
    u16* __restrict__ w1sp, u16* __restrict__ w2sp, u16* __restrict__ wpsp)
{
    const int T1 = 4 * 128 * 72;   // 36864
    const int T2 = 2 * 64 * 72;    // 9216
    const int T3 = 1 * 64 * 72;    // 4608
    int idx = blockIdx.x * 256 + threadIdx.x;
    if (idx < T1)                 wsplit_one(W1, w1sp, 256, 128, idx);
    else if (idx < T1 + T2)       wsplit_one(W2, w2sp, 128, 64, idx - T1);
    else if (idx < T1 + T2 + T3)  wsplit_one(Wp, wpsp, 64, 64, idx - T1 - T2);
}

// ---------- Pass A: bin entries into fixed-capacity bucket regions ----------
// Bucket = id >> 7. Temp entry: ((id&127)<<16) | value (ids < 65536).
// Index layout (int32 vs int64-words) detected per block by wave 0.
__global__ __launch_bounds__(256) void bin_scatter_kernel(
    const int* __restrict__ hidx,
    int* __restrict__ curEb, int* __restrict__ curNb,
    u32* __restrict__ tmpE, u32* __restrict__ tmpN,
    int nnz, int nNodes, int nEdges)
{
    __shared__ int histE[400], histN[400];
    __shared__ int s_st;
    int t = threadIdx.x;
    const int nbE = (nEdges + 127) >> 7, nbN = (nNodes + 127) >> 7;
    for (int b = t; b < 400; b += 256) { histE[b] = 0; histN[b] = 0; }
    if (t < 64) {
        unsigned long long m = __ballot(hidx[2 * t + 1] != 0);
        if (t == 0) s_st = (m == 0ull) ? 2 : 1;   // all-zero odd words -> int64 layout
    }
    __syncthreads();
    int st = s_st;
    size_t eoff = (size_t)nnz * st;
    int i0 = blockIdx.x * 4096;
    int e_[16], n_[16]; int rE[16], rN[16];
    #pragma unroll
    for (int k = 0; k < 16; ++k) {
        int i = i0 + k * 256 + t;
        int n = -1, e = 0;
        if (i < nnz) {
            n = hidx[(size_t)i * st];
            e = hidx[eoff + (size_t)i * st];
            if (!((u32)n < (u32)nNodes && (u32)e < (u32)nEdges)) n = -1;
        }
        n_[k] = n; e_[k] = e;
        if (n >= 0) {
            rE[k] = atomicAdd(&histE[e >> 7], 1);
            rN[k] = atomicAdd(&histN[n >> 7], 1);
        }
    }
    __syncthreads();
    for (int b = t; b < nbE; b += 256) { int c = histE[b]; if (c) histE[b] = atomicAdd(&curEb[b], c); }
    for (int b = t; b < nbN; b += 256) { int c = histN[b]; if (c) histN[b] = atomicAdd(&curNb[b], c); }
    __syncthreads();
    #pragma unroll
    for (int k = 0; k < 16; ++k) {
        if (n_[k] >= 0) {
            int e = e_[k], n = n_[k];
            int lpE = histE[e >> 7] + rE[k];
            int lpN = histN[n >> 7] + rN[k];
            if (lpE < BCAP) tmpE[(size_t)(e >> 7) * BCAP + lpE] = ((u32)(e & 127) << 16) | (u32)n;
            if (lpN < BCAP) tmpN[(size_t)(n >> 7) * BCAP + lpN] = ((u32)(n & 127) << 16) | (u32)e;
        }
    }
}

// ---------- scan bucket counts -> global CSR bases (block 0: edges, block 1: nodes) ----------
__global__ __launch_bounds__(64) void bkt_scan_kernel(
    const int* __restrict__ curE, const int* __restrict__ curN,
    int* __restrict__ baseE, int* __restrict__ baseN, int nbE, int nbN)
{
    const int* cur; int* base; int nb;
    if (blockIdx.x == 0) { cur = curE; base = baseE; nb = nbE; }
    else                 { cur = curN; base = baseN; nb = nbN; }
    int lane = threadIdx.x;
    int carry = 0;
    for (int c0 = 0; c0 < nb; c0 += 64) {
        int i = c0 + lane;
        int v = (i < nb) ? cur[i] : 0;
        int orig = v;
        for (int o = 1; o < 64; o <<= 1) { int u = __shfl_up(v, o, 64); if (lane >= o) v += u; }
        if (i < nb) base[i] = carry + v - orig;   // exclusive
        carry += __shfl(v, 63, 64);
    }
    if (lane == 0) base[nb] = carry;
}

// ---------- Pass B: per bucket, compute deg/offs/inv + CSR-ordered adj (all coalesced) ----------
__global__ __launch_bounds__(256) void bin_build_kernel(
    const u32* __restrict__ tmpE, const u32* __restrict__ tmpN,
    const int* __restrict__ baseE, const int* __restrict__ baseN,
    int* __restrict__ deg_e, int* __restrict__ offs_e, float* __restrict__ binv, u16* __restrict__ adj_e,
    int* __restrict__ deg_n, int* __restrict__ offs_n, float* __restrict__ dinv, u16* __restrict__ adj_n,
    int nE, int nN, int nbE)
{
    __shared__ u32 buf[4096];
    __shared__ int lcnt[128], lpre[128], lcur[128];
    int b = blockIdx.x;
    const u32* tmp; const int* base; int* deg; int* offs; float* inv; u16* adj; int n, tb;
    if (b < nbE) { tmp=tmpE; base=baseE; deg=deg_e; offs=offs_e; inv=binv; adj=adj_e; n=nE; tb=b; }
    else         { tmp=tmpN; base=baseN; deg=deg_n; offs=offs_n; inv=dinv; adj=adj_n; n=nN; tb=b-nbE; }
    int t = threadIdx.x;
    int g0 = tb << 7;
    int gbase = base[tb];
    int cnt = base[tb + 1] - gbase;
    int avail = cnt < BCAP ? cnt : BCAP;          // drop-guard (never hit for sane data)
    size_t tbase = (size_t)tb * BCAP;
    if (t < 128) lcnt[t] = 0;
    __syncthreads();
    for (int j = t; j < avail; j += 256) atomicAdd(&lcnt[tmp[tbase + j] >> 16], 1);
    __syncthreads();
    if (t < 64) {                                  // 128-wide exclusive prefix, one wave x2
        int a0 = lcnt[2 * t], a1 = lcnt[2 * t + 1];
        int ps = a0 + a1, v = ps;
        for (int o = 1; o < 64; o <<= 1) { int u = __shfl_up(v, o, 64); if (t >= o) v += u; }
        int excl = v - ps;
        lpre[2 * t] = excl; lpre[2 * t + 1] = excl + a0;
    }
    __syncthreads();
    if (t < 128) {
        int id = g0 + t;
        if (id < n) {
            int d = lcnt[t];
            deg[id]  = d;
            offs[id] = gbase + lpre[t];
            inv[id]  = d > 0 ? 1.0f / (float)d : 0.0f;
        }
        lcur[t] = lpre[t];
    }
    __syncthreads();
    if (avail <= 0) return;
    for (int j = t; j < avail; j += 256) {
        u32 v = tmp[tbase + j];
        int pos = atomicAdd(&lcur[v >> 16], 1);
        buf[pos] = v & 0xFFFFu;
    }
    __syncthreads();
    for (int j = t; j < avail; j += 256) adj[gbase + j] = (u16)buf[j];
}

// ---------- XCD-sliced segment gather-sum over plane-major f16, f32 accumulation ----------
// src layout: [8 planes][nSrcRows][SW] f16. plane = blockIdx&7 -> pinned to one XCD
// (round-robin dispatch), per-XCD working set = nSrcRows*SW*2 bytes (L2-resident).
template<int SW, bool FINAL, int C>
__global__ __launch_bounds__(256) void gather_slice_kernel(
    const f16* __restrict__ src, const u16* __restrict__ adj,
    const int* __restrict__ offs, const int* __restrict__ deg,
    const float* __restrict__ inv, const float* __restrict__ bias,
    void* __restrict__ dstv, int nRows, int nSrcRows)
{
    constexpr int TPR = SW / 8;             // threads per row (2 for SW=16, 1 for SW=8)
    constexpr int RPB = 256 / TPR;          // rows per block
    int t = threadIdx.x;
    int plane = blockIdx.x & 7;
    int chunk = blockIdx.x >> 3;
    int r = chunk * RPB + t / TPR;
    if (r >= nRows) return;
    int sub = (TPR == 2) ? (t & 1) : 0;
    const f16* sp = src + (size_t)plane * nSrcRows * SW + sub * 8;
    int j = offs[r], e = j + deg[r];
    float a0[8], a1[8], a2[8], a3[8];
    #pragma unroll
    for (int q = 0; q < 8; ++q) { a0[q] = 0.f; a1[q] = 0.f; a2[q] = 0.f; a3[q] = 0.f; }
    for (; j + 4 <= e; j += 4) {
        int s0 = adj[j], s1 = adj[j + 1], s2 = adj[j + 2], s3 = adj[j + 3];
        const half8 v0 = *(const half8*)(sp + (size_t)s0 * SW);
        const half8 v1 = *(const half8*)(sp + (size_t)s1 * SW);
        const half8 v2 = *(const half8*)(sp + (size_t)s2 * SW);
        const half8 v3 = *(const half8*)(sp + (size_t)s3 * SW);
        #pragma unroll
        for (int q = 0; q < 8; ++q) {
            a0[q] += (float)v0[q]; a1[q] += (float)v1[q];
            a2[q] += (float)v2[q]; a3[q] += (float)v3[q];
        }
    }
    for (; j < e; ++j) {
        int s0 = adj[j];
        const half8 v0 = *(const half8*)(sp + (size_t)s0 * SW);
        #pragma unroll
        for (int q = 0; q < 8; ++q) a0[q] += (float)v0[q];
    }
    float scv = inv[r];
    float rr[8];
    #pragma unroll
    for (int q = 0; q < 8; ++q) rr[q] = ((a0[q] + a1[q]) + (a2[q] + a3[q])) * scv;
    if constexpr (FINAL) {
        float* dst = (float*)dstv;
        size_t o = (size_t)r * C + plane * SW + sub * 8;
        const float* bp = bias + plane * SW + sub * 8;
        const float4 b0 = *(const float4*)(bp);
        const float4 b1 = *(const float4*)(bp + 4);
        float4 o0, o1;
        o0.x = fmaxf(rr[0] + b0.x, 0.0f); o0.y = fmaxf(rr[1] + b0.y, 0.0f);
        o0.z = fmaxf(rr[2] + b0.z, 0.0f); o0.w = fmaxf(rr[3] + b0.w, 0.0f);
        o1.x = fmaxf(rr[4] + b1.x, 0.0f); o1.y = fmaxf(rr[5] + b1.y, 0.0f);
        o1.z = fmaxf(rr[6] + b1.z, 0.0f); o1.w = fmaxf(rr[7] + b1.w, 0.0f);
        *(float4*)(dst + o)     = o0;
        *(float4*)(dst + o + 4) = o1;
    } else {
        f16* dst = (f16*)dstv;
        half8 ov;
        #pragma unroll
        for (int q = 0; q < 8; ++q) ov[q] = (f16)rr[q];
        *(half8*)(dst + (size_t)plane * nRows * SW + (size_t)r * SW + sub * 8) = ov;
    }
}

// ---------- persistent MFMA split-bf16 GEMM, whole pre-split B in LDS ----------
// C[M,N] = A[M,K] @ B[K,N] (+bias). A f32; B pre-split [K/64][2][N][72] bf16.
// 1024 threads = 16 waves: 8 row-groups x 2 N-halves = 128 rows/tile.
// B staged once, single barrier, then barrier-free loop over row-tiles.
// OUT: 0 = f32 row-major, 1 = f16 plane-major SW=16, 2 = f16 plane-major SW=8.
__device__ __forceinline__ void split8(const float* __restrict__ p, short8& hi, short8& lo) {
    #pragma unroll
    for (int j = 0; j < 8; ++j) {
        float v = p[j];
        u16 h = f2bf(v);
        hi[j] = (short)h;
        lo[j] = (short)f2bf(v - bf2f(h));
    }
}

template<int K, int N, bool BIAS, int OUT>
__global__ __launch_bounds__(1024) void gemm_mfma_kernel(
    const float* __restrict__ A, const u16* __restrict__ Bsp,
    const float* __restrict__ bias, void* __restrict__ C_, int M)
{
    constexpr int KP = 72;
    constexpr int NCH = K / 64;
    constexpr int CHUNK = 2 * N * KP;              // u16 per 64-k chunk (hi+lo)
    constexpr int NTW = N / 32;                    // n-tiles per wave
    __shared__ alignas(16) u16 Bbuf[NCH * CHUNK];  // K=256,N=128 -> 144KB
    const int tid = threadIdx.x;
    constexpr int U = NCH * CHUNK / 8;             // 16B units
    for (int u = tid; u < U; u += 1024)
        *(float4*)(&Bbuf[(size_t)u * 8]) = *(const float4*)(Bsp + (size_t)u * 8);
    __syncthreads();
    const int wave = tid >> 6, lane = tid & 63;
    const int mg = wave >> 1, nh = wave & 1;
    const int lr = lane & 15, kq = (lane >> 4) * 8;
    const int nt0 = nh * NTW;
    const int MT = (M + 127) >> 7;
    for (int tile = blockIdx.x; tile < MT; tile += gridDim.x) {
        const int row0 = tile * 128 + mg * 16;
        if (row0 >= M) continue;                   // no barriers in loop -> divergence safe
        f32x4 acc[NTW];
        #pragma unroll
        for (int i = 0; i < NTW; ++i) acc[i] = (f32x4){0.f, 0.f, 0.f, 0.f};
        const float* Ap = A + (size_t)(row0 + lr) * K + kq;
        #pragma unroll
        for (int c = 0; c < NCH; ++c) {
            #pragma unroll
            for (int k0 = 0; k0 < 64; k0 += 32) {
                short8 ah, al;
                split8(Ap + c * 64 + k0, ah, al);
                #pragma unroll
                for (int f = 0; f < NTW; ++f) {
                    const int col = (nt0 + f) * 16 + lr;
                    const int bo = c * CHUNK + col * KP + k0 + kq;
                    const short8 bh = *(const short8*)(&Bbuf[bo]);
                    const short8 bl = *(const short8*)(&Bbuf[bo + N * KP]);
                    acc[f] = __builtin_amdgcn_mfma_f32_16x16x32_bf16(ah, bh, acc[f], 0, 0, 0);
                    acc[f] = __builtin_amdgcn_mfma_f32_16x16x32_bf16(al, bh, acc[f], 0, 0, 0);
                    acc[f] = __builtin_amdgcn_mfma_f32_16x16x32_bf16(ah, bl, acc[f], 0, 0, 0);
                }
            }
        }
        const int orow = row0 + (lane >> 4) * 4;
        #pragma unroll
        for (int f = 0; f < NTW; ++f) {
            const int col = (nt0 + f) * 16 + lr;
            float bv = 0.0f;
            if constexpr (BIAS) bv = bias[col];
            #pragma unroll
            for (int j = 0; j < 4; ++j) {
                float vv = acc[f][j] + bv;
                if constexpr (OUT == 0) {
                    ((float*)C_)[(size_t)(orow + j) * N + col] = vv;
                } else if constexpr (OUT == 1) {   // planes of 16 ch: plane = nt0+f, ip = lr
                    ((f16*)C_)[((size_t)(nt0 + f) * M + (orow + j)) * 16 + lr] = (f16)vv;
                } else {                           // planes of 8 ch
                    const int plane = (nt0 + f) * 2 + (lr >> 3);
                    ((f16*)C_)[((size_t)plane * M + (orow + j)) * 8 + (lr & 7)] = (f16)vv;
                }
            }
        }
    }
}

// ---------- launcher ----------
extern "C" void kernel_launch(void* const* d_in, const int* in_sizes, int n_in,
                              void* d_out, int out_size, void* d_ws, size_t ws_size,
                              hipStream_t stream)
{
    (void)n_in; (void)out_size; (void)ws_size;
    const float* x  = (const float*)d_in[0];
    const int* hidx = (const int*)d_in[1];
    const float* W1 = (const float*)d_in[2];
    const float* b1 = (const float*)d_in[3];
    const float* W2 = (const float*)d_in[4];
    const float* b2 = (const float*)d_in[5];
    const float* Wp = (const float*)d_in[6];
    const float* bp = (const float*)d_in[7];
    float* out = (float*)d_out;

    const int nnz    = in_sizes[1] / 2;    // 800000
    const int nNodes = in_sizes[0] / 256;  // 50000
    const int nEdges = 50000;              // N_EDGES (not derivable from inputs)

    char* w = (char*)d_ws;
    const size_t SEG = 200192;             // >= 50048*4, 256B aligned
    int*   deg_e  = (int*)(w + 0 * SEG);
    int*   deg_n  = (int*)(w + 1 * SEG);
    int*   offs_e = (int*)(w + 2 * SEG);
    int*   offs_n = (int*)(w + 3 * SEG);
    float* binv   = (float*)(w + 4 * SEG);
    float* dinv   = (float*)(w + 5 * SEG);
    int*   curEb  = (int*)(w + 6 * SEG + 256);    // 391 ints
    int*   curNb  = (int*)(w + 6 * SEG + 2304);   // 391 ints
    int*   baseE  = (int*)(w + 6 * SEG + 4352);   // 392 ints
    int*   baseN  = (int*)(w + 6 * SEG + 6400);   // 392 ints
    char* p = w + 6 * SEG + 8448;
    u16* adj_e = (u16*)p;  p += (size_t)nnz * 2;              // 1.6 MB
    u16* adj_n = (u16*)p;  p += (size_t)nnz * 2;              // 1.6 MB
    f16* h0  = (f16*)p;                                       // 8 planes x 50000 x 16 f16
    f16* m1  = (f16*)(p + (size_t)nNodes * 128 * 2);          // 8 planes x 50000 x 16 f16
    f16* h1w = h0;                                            // reuse: 8 planes x 50000 x 8
    f16* m2  = (f16*)((char*)h0 + (size_t)nNodes * 64 * 2);   // disjoint from h1w
    // pre-split weight images after m1 region
    u16* w1sp = (u16*)(p + 2 * (size_t)nNodes * 128 * 2);     // 4 chunks * 18432 u16
    u16* w2sp = w1sp + 4 * 18432;                             // 2 chunks * 9216 u16
    u16* wpsp = w2sp + 2 * 9216;                              // 1 chunk  * 9216 u16

    const int nbE = (nEdges + 127) >> 7;             // 391
    const int nbN = (nNodes + 127) >> 7;             // 391
    // tmp bucket regions alias m1 (dead until gather1 writes it, after bin_build)
    u32* tmpE = (u32*)m1;
    u32* tmpN = tmpE + (size_t)nbE * BCAP;

    const size_t F1OFF = (size_t)nNodes * 64;        // out: z | f1 | f2 (f32)
    const size_t F2OFF = F1OFF + (size_t)nNodes * 128;

    hipMemsetAsync(w + 6 * SEG + 256, 0, 4096, stream);   // zero bucket cursors
    wsplit_all_kernel<<<(4*128*72 + 2*64*72 + 1*64*72 + 255) / 256, 256, 0, stream>>>(
        W1, W2, Wp, w1sp, w2sp, wpsp);
    bin_scatter_kernel<<<(nnz + 4095) / 4096, 256, 0, stream>>>(
        hidx, curEb, curNb, tmpE, tmpN, nnz, nNodes, nEdges);
    bkt_scan_kernel<<<2, 64, 0, stream>>>(curEb, curNb, baseE, baseN, nbE, nbN);
    bin_build_kernel<<<nbE + nbN, 256, 0, stream>>>(
        tmpE, tmpN, baseE, baseN,
        deg_e, offs_e, binv, adj_e,
        deg_n, offs_n, dinv, adj_n,
        nEdges, nNodes, nbE);

    // layer 1: h0 = x @ W1 (f16 planes SW=16)
    gemm_mfma_kernel<256, 128, false, 1><<<256, 1024, 0, stream>>>(x, w1sp, nullptr, h0, nNodes);
    gather_slice_kernel<16, false, 128><<<((nEdges + 127) / 128) * 8, 256, 0, stream>>>(
        h0, adj_e, offs_e, deg_e, binv, nullptr, m1, nEdges, nNodes);
    gather_slice_kernel<16, true, 128><<<((nNodes + 127) / 128) * 8, 256, 0, stream>>>(
        m1, adj_n, offs_n, deg_n, dinv, b1, out + F1OFF, nNodes, nEdges);

    // layer 2: h1w = f1 @ W2 (f16 planes SW=8)
    gemm_mfma_kernel<128, 64, false, 2><<<391, 1024, 0, stream>>>(
        out + F1OFF, w2sp, nullptr, h1w, nNodes);
    gather_slice_kernel<8, false, 64><<<((nEdges + 255) / 256) * 8, 256, 0, stream>>>(
        h1w, adj_e, offs_e, deg_e, binv, nullptr, m2, nEdges, nNodes);
    gather_slice_kernel<8, true, 64><<<((nNodes + 255) / 256) * 8, 256, 0, stream>>>(
        m2, adj_n, offs_n, deg_n, dinv, b2, out + F2OFF, nNodes, nEdges);

    // projection: z = f2 @ Wp + bp (f32 row-major)
    gemm_mfma_kernel<64, 64, true, 0><<<391, 1024, 0, stream>>>(
        out + F2OFF, wpsp, bp, out, nNodes);
}

// Round 4
// 274.224 us; speedup vs baseline: 1.1982x; 1.1982x over previous
//
#include <hip/hip_runtime.h>

// f32 in/out pipeline: MFMA split-bf16 GEMMs + CSR gathers.
// Round 12: gathers are L2-request-bound, not HBM-bound (R3: FETCH 15MB, 12%
// peak, yet 41.6us). SW=16 planes (32B rows) wasted half of every 64B line and
// doubled line-touches. Now SW=32 planes (64B rows): one fully-used line per
// random access. C=128 -> 4 planes (XCDs {p,p+4}, 3.2MB/XCD working set),
// C=64 -> 2 planes. Persistent GEMMs (B fully LDS-resident) unchanged.

typedef unsigned short u16;
typedef unsigned int   u32;
typedef _Float16 f16;
typedef __attribute__((ext_vector_type(8))) short short8;     // 8 bf16 (4 VGPRs)
typedef __attribute__((ext_vector_type(8))) _Float16 half8;   // 8 f16 (16B)
typedef __attribute__((ext_vector_type(4))) float f32x4;      // MFMA C/D frag

static const int BCAP = 3072;   // tmp capacity per 128-id bucket (mean fill ~2046)

__device__ __forceinline__ float bf2f(u16 u) {
    return __builtin_bit_cast(float, (u32)u << 16);
}
__device__ __forceinline__ u16 f2bf(float f) {
    u32 b = __builtin_bit_cast(u32, f);
    b += 0x7FFFu + ((b >> 16) & 1u);   // RNE (finite)
    return (u16)(b >> 16);
}

// ---------- one-time weight split: W[K,N] f32 -> [K/64][2][N][72] bf16 hi/lo ----------
__device__ __forceinline__ void wsplit_one(const float* __restrict__ W, u16* __restrict__ out,
                                           int K, int N, int local)
{
    int kp = local % 72;
    int rest = local / 72;
    int n = rest % N;
    int c = rest / N;
    float v = 0.f;
    if (kp < 64) v = W[(size_t)(c * 64 + kp) * N + n];
    u16 h = f2bf(v);
    u16 l = f2bf(v - bf2f(h));
    size_t base = (size_t)c * (2 * (size_t)N * 72);
    out[base + (size_t)n * 72 + kp] = h;
    out[base + (size_t)N * 72 + (size_t)n * 72 + kp] = l;
}

__global__ __launch_bounds__(256) void wsplit_all_kernel(
    const float* __restrict__ W1, const float* __restrict__ W2, const float* __restrict__ Wp,
    u16* __restrict__ w1sp, u16* __restrict__ w2sp, u16* __restrict__ wpsp)
{
    const int T1 = 4 * 128 * 72;   // 36864
    const int T2 = 2 * 64 * 72;    // 9216
    const int T3 = 1 * 64 * 72;    // 4608
    int idx = blockIdx.x * 256 + threadIdx.x;
    if (idx < T1)                 wsplit_one(W1, w1sp, 256, 128, idx);
    else if (idx < T1 + T2)       wsplit_one(W2, w2sp, 128, 64, idx - T1);
    else if (idx < T1 + T2 + T3)  wsplit_one(Wp, wpsp, 64, 64, idx - T1 - T2);
}

// ---------- Pass A: bin entries into fixed-capacity bucket regions ----------
// Bucket = id >> 7. Temp entry: ((id&127)<<16) | value (ids < 65536).
// Index layout (int32 vs int64-words) detected per block by wave 0.
__global__ __launch_bounds__(256) void bin_scatter_kernel(
    const int* __restrict__ hidx,
    int* __restrict__ curEb, int* __restrict__ curNb,
    u32* __restrict__ tmpE, u32* __restrict__ tmpN,
    int nnz, int nNodes, int nEdges)
{
    __shared__ int histE[400], histN[400];
    __shared__ int s_st;
    int t = threadIdx.x;
    const int nbE = (nEdges + 127) >> 7, nbN = (nNodes + 127) >> 7;
    for (int b = t; b < 400; b += 256) { histE[b] = 0; histN[b] = 0; }
    if (t < 64) {
        unsigned long long m = __ballot(hidx[2 * t + 1] != 0);
        if (t == 0) s_st = (m == 0ull) ? 2 : 1;   // all-zero odd words -> int64 layout
    }
    __syncthreads();
    int st = s_st;
    size_t eoff = (size_t)nnz * st;
    int i0 = blockIdx.x * 4096;
    int e_[16], n_[16]; int rE[16], rN[16];
    #pragma unroll
    for (int k = 0; k < 16; ++k) {
        int i = i0 + k * 256 + t;
        int n = -1, e = 0;
        if (i < nnz) {
            n = hidx[(size_t)i * st];
            e = hidx[eoff + (size_t)i * st];
            if (!((u32)n < (u32)nNodes && (u32)e < (u32)nEdges)) n = -1;
        }
        n_[k] = n; e_[k] = e;
        if (n >= 0) {
            rE[k] = atomicAdd(&histE[e >> 7], 1);
            rN[k] = atomicAdd(&histN[n >> 7], 1);
        }
    }
    __syncthreads();
    for (int b = t; b < nbE; b += 256) { int c = histE[b]; if (c) histE[b] = atomicAdd(&curEb[b], c); }
    for (int b = t; b < nbN; b += 256) { int c = histN[b]; if (c) histN[b] = atomicAdd(&curNb[b], c); }
    __syncthreads();
    #pragma unroll
    for (int k = 0; k < 16; ++k) {
        if (n_[k] >= 0) {
            int e = e_[k], n = n_[k];
            int lpE = histE[e >> 7] + rE[k];
            int lpN = histN[n >> 7] + rN[k];
            if (lpE < BCAP) tmpE[(size_t)(e >> 7) * BCAP + lpE] = ((u32)(e & 127) << 16) | (u32)n;
            if (lpN < BCAP) tmpN[(size_t)(n >> 7) * BCAP + lpN] = ((u32)(n & 127) << 16) | (u32)e;
        }
    }
}

// ---------- scan bucket counts -> global CSR bases (block 0: edges, block 1: nodes) ----------
__global__ __launch_bounds__(64) void bkt_scan_kernel(
    const int* __restrict__ curE, const int* __restrict__ curN,
    int* __restrict__ baseE, int* __restrict__ baseN, int nbE, int nbN)
{
    const int* cur; int* base; int nb;
    if (blockIdx.x == 0) { cur = curE; base = baseE; nb = nbE; }
    else                 { cur = curN; base = baseN; nb = nbN; }
    int lane = threadIdx.x;
    int carry = 0;
    for (int c0 = 0; c0 < nb; c0 += 64) {
        int i = c0 + lane;
        int v = (i < nb) ? cur[i] : 0;
        int orig = v;
        for (int o = 1; o < 64; o <<= 1) { int u = __shfl_up(v, o, 64); if (lane >= o) v += u; }
        if (i < nb) base[i] = carry + v - orig;   // exclusive
        carry += __shfl(v, 63, 64);
    }
    if (lane == 0) base[nb] = carry;
}

// ---------- Pass B: per bucket, compute deg/offs/inv + CSR-ordered adj (all coalesced) ----------
__global__ __launch_bounds__(256) void bin_build_kernel(
    const u32* __restrict__ tmpE, const u32* __restrict__ tmpN,
    const int* __restrict__ baseE, const int* __restrict__ baseN,
    int* __restrict__ deg_e, int* __restrict__ offs_e, float* __restrict__ binv, u16* __restrict__ adj_e,
    int* __restrict__ deg_n, int* __restrict__ offs_n, float* __restrict__ dinv, u16* __restrict__ adj_n,
    int nE, int nN, int nbE)
{
    __shared__ u32 buf[4096];
    __shared__ int lcnt[128], lpre[128], lcur[128];
    int b = blockIdx.x;
    const u32* tmp; const int* base; int* deg; int* offs; float* inv; u16* adj; int n, tb;
    if (b < nbE) { tmp=tmpE; base=baseE; deg=deg_e; offs=offs_e; inv=binv; adj=adj_e; n=nE; tb=b; }
    else         { tmp=tmpN; base=baseN; deg=deg_n; offs=offs_n; inv=dinv; adj=adj_n; n=nN; tb=b-nbE; }
    int t = threadIdx.x;
    int g0 = tb << 7;
    int gbase = base[tb];
    int cnt = base[tb + 1] - gbase;
    int avail = cnt < BCAP ? cnt : BCAP;          // drop-guard (never hit for sane data)
    size_t tbase = (size_t)tb * BCAP;
    if (t < 128) lcnt[t] = 0;
    __syncthreads();
    for (int j = t; j < avail; j += 256) atomicAdd(&lcnt[tmp[tbase + j] >> 16], 1);
    __syncthreads();
    if (t < 64) {                                  // 128-wide exclusive prefix, one wave x2
        int a0 = lcnt[2 * t], a1 = lcnt[2 * t + 1];
        int ps = a0 + a1, v = ps;
        for (int o = 1; o < 64; o <<= 1) { int u = __shfl_up(v, o, 64); if (t >= o) v += u; }
        int excl = v - ps;
        lpre[2 * t] = excl; lpre[2 * t + 1] = excl + a0;
    }
    __syncthreads();
    if (t < 128) {
        int id = g0 + t;
        if (id < n) {
            int d = lcnt[t];
            deg[id]  = d;
            offs[id] = gbase + lpre[t];
            inv[id]  = d > 0 ? 1.0f / (float)d : 0.0f;
        }
        lcur[t] = lpre[t];
    }
    __syncthreads();
    if (avail <= 0) return;
    for (int j = t; j < avail; j += 256) {
        u32 v = tmp[tbase + j];
        int pos = atomicAdd(&lcur[v >> 16], 1);
        buf[pos] = v & 0xFFFFu;
    }
    __syncthreads();
    for (int j = t; j < avail; j += 256) adj[gbase + j] = (u16)buf[j];
}

// ---------- XCD-sliced segment gather-sum, SW=32 planes (64B rows) ----------
// src layout: [NP planes][nSrcRows][32] f16. plane = blockIdx & (NP-1); with
// round-robin block->XCD dispatch each plane's 3.2MB working set stays in the
// L2(s) of the XCDs it lands on. One random access = one fully-used 64B line.
template<int NP, bool FINAL, int C>
__global__ __launch_bounds__(256) void gather_slice_kernel(
    const f16* __restrict__ src, const u16* __restrict__ adj,
    const int* __restrict__ offs, const int* __restrict__ deg,
    const float* __restrict__ inv, const float* __restrict__ bias,
    void* __restrict__ dstv, int nRows, int nSrcRows)
{
    constexpr int SW = 32;                  // channels per plane
    constexpr int TPR = 4;                  // 4 lanes x 8 f16 = 64B row
    constexpr int RPB = 64;                 // rows per block
    int t = threadIdx.x;
    int plane = blockIdx.x & (NP - 1);
    int chunk = blockIdx.x / NP;
    int r = chunk * RPB + t / TPR;
    if (r >= nRows) return;
    int sub = t & 3;
    const f16* sp = src + (size_t)plane * nSrcRows * SW + sub * 8;
    int j = offs[r], e = j + deg[r];
    float a0[8], a1[8], a2[8], a3[8];
    #pragma unroll
    for (int q = 0; q < 8; ++q) { a0[q] = 0.f; a1[q] = 0.f; a2[q] = 0.f; a3[q] = 0.f; }
    for (; j + 4 <= e; j += 4) {
        int s0 = adj[j], s1 = adj[j + 1], s2 = adj[j + 2], s3 = adj[j + 3];
        const half8 v0 = *(const half8*)(sp + (size_t)s0 * SW);
        const half8 v1 = *(const half8*)(sp + (size_t)s1 * SW);
        const half8 v2 = *(const half8*)(sp + (size_t)s2 * SW);
        const half8 v3 = *(const half8*)(sp + (size_t)s3 * SW);
        #pragma unroll
        for (int q = 0; q < 8; ++q) {
            a0[q] += (float)v0[q]; a1[q] += (float)v1[q];
            a2[q] += (float)v2[q]; a3[q] += (float)v3[q];
        }
    }
    for (; j < e; ++j) {
        int s0 = adj[j];
        const half8 v0 = *(const half8*)(sp + (size_t)s0 * SW);
        #pragma unroll
        for (int q = 0; q < 8; ++q) a0[q] += (float)v0[q];
    }
    float scv = inv[r];
    float rr[8];
    #pragma unroll
    for (int q = 0; q < 8; ++q) rr[q] = ((a0[q] + a1[q]) + (a2[q] + a3[q])) * scv;
    if constexpr (FINAL) {
        float* dst = (float*)dstv;
        size_t o = (size_t)r * C + plane * SW + sub * 8;
        const float* bp = bias + plane * SW + sub * 8;
        const float4 b0 = *(const float4*)(bp);
        const float4 b1 = *(const float4*)(bp + 4);
        float4 o0, o1;
        o0.x = fmaxf(rr[0] + b0.x, 0.0f); o0.y = fmaxf(rr[1] + b0.y, 0.0f);
        o0.z = fmaxf(rr[2] + b0.z, 0.0f); o0.w = fmaxf(rr[3] + b0.w, 0.0f);
        o1.x = fmaxf(rr[4] + b1.x, 0.0f); o1.y = fmaxf(rr[5] + b1.y, 0.0f);
        o1.z = fmaxf(rr[6] + b1.z, 0.0f); o1.w = fmaxf(rr[7] + b1.w, 0.0f);
        *(float4*)(dst + o)     = o0;
        *(float4*)(dst + o + 4) = o1;
    } else {
        f16* dst = (f16*)dstv;
        half8 ov;
        #pragma unroll
        for (int q = 0; q < 8; ++q) ov[q] = (f16)rr[q];
        *(half8*)(dst + ((size_t)plane * nRows + r) * SW + sub * 8) = ov;
    }
}

// ---------- persistent MFMA split-bf16 GEMM, whole pre-split B in LDS ----------
// C[M,N] = A[M,K] @ B[K,N] (+bias). A f32; B pre-split [K/64][2][N][72] bf16.
// 1024 threads = 16 waves: 8 row-groups x 2 N-halves = 128 rows/tile.
// B staged once, single barrier, then barrier-free loop over row-tiles.
// OUT: 0 = f32 row-major, 1 = f16 plane-major SW=32 (plane = col>>5).
__device__ __forceinline__ void split8(const float* __restrict__ p, short8& hi, short8& lo) {
    #pragma unroll
    for (int j = 0; j < 8; ++j) {
        float v = p[j];
        u16 h = f2bf(v);
        hi[j] = (short)h;
        lo[j] = (short)f2bf(v - bf2f(h));
    }
}

template<int K, int N, bool BIAS, int OUT>
__global__ __launch_bounds__(1024) void gemm_mfma_kernel(
    const float* __restrict__ A, const u16* __restrict__ Bsp,
    const float* __restrict__ bias, void* __restrict__ C_, int M)
{
    constexpr int KP = 72;
    constexpr int NCH = K / 64;
    constexpr int CHUNK = 2 * N * KP;              // u16 per 64-k chunk (hi+lo)
    constexpr int NTW = N / 32;                    // n-tiles per wave
    __shared__ alignas(16) u16 Bbuf[NCH * CHUNK];  // K=256,N=128 -> 144KB
    const int tid = threadIdx.x;
    constexpr int U = NCH * CHUNK / 8;             // 16B units
    for (int u = tid; u < U; u += 1024)
        *(float4*)(&Bbuf[(size_t)u * 8]) = *(const float4*)(Bsp + (size_t)u * 8);
    __syncthreads();
    const int wave = tid >> 6, lane = tid & 63;
    const int mg = wave >> 1, nh = wave & 1;
    const int lr = lane & 15, kq = (lane >> 4) * 8;
    const int nt0 = nh * NTW;
    const int MT = (M + 127) >> 7;
    for (int tile = blockIdx.x; tile < MT; tile += gridDim.x) {
        const int row0 = tile * 128 + mg * 16;
        if (row0 >= M) continue;                   // no barriers in loop -> divergence safe
        f32x4 acc[NTW];
        #pragma unroll
        for (int i = 0; i < NTW; ++i) acc[i] = (f32x4){0.f, 0.f, 0.f, 0.f};
        const float* Ap = A + (size_t)(row0 + lr) * K + kq;
        #pragma unroll
        for (int c = 0; c < NCH; ++c) {
            #pragma unroll
            for (int k0 = 0; k0 < 64; k0 += 32) {
                short8 ah, al;
                split8(Ap + c * 64 + k0, ah, al);
                #pragma unroll
                for (int f = 0; f < NTW; ++f) {
                    const int col = (nt0 + f) * 16 + lr;
                    const int bo = c * CHUNK + col * KP + k0 + kq;
                    const short8 bh = *(const short8*)(&Bbuf[bo]);
                    const short8 bl = *(const short8*)(&Bbuf[bo + N * KP]);
                    acc[f] = __builtin_amdgcn_mfma_f32_16x16x32_bf16(ah, bh, acc[f], 0, 0, 0);
                    acc[f] = __builtin_amdgcn_mfma_f32_16x16x32_bf16(al, bh, acc[f], 0, 0, 0);
                    acc[f] = __builtin_amdgcn_mfma_f32_16x16x32_bf16(ah, bl, acc[f], 0, 0, 0);
                }
            }
        }
        const int orow = row0 + (lane >> 4) * 4;
        #pragma unroll
        for (int f = 0; f < NTW; ++f) {
            const int col = (nt0 + f) * 16 + lr;
            float bv = 0.0f;
            if constexpr (BIAS) bv = bias[col];
            #pragma unroll
            for (int j = 0; j < 4; ++j) {
                float vv = acc[f][j] + bv;
                if constexpr (OUT == 0) {
                    ((float*)C_)[(size_t)(orow + j) * N + col] = vv;
                } else {                           // f16 planes of 32 channels
                    ((f16*)C_)[((size_t)(col >> 5) * M + (orow + j)) * 32 + (col & 31)] = (f16)vv;
                }
            }
        }
    }
}

// ---------- launcher ----------
extern "C" void kernel_launch(void* const* d_in, const int* in_sizes, int n_in,
                              void* d_out, int out_size, void* d_ws, size_t ws_size,
                              hipStream_t stream)
{
    (void)n_in; (void)out_size; (void)ws_size;
    const float* x  = (const float*)d_in[0];
    const int* hidx = (const int*)d_in[1];
    const float* W1 = (const float*)d_in[2];
    const float* b1 = (const float*)d_in[3];
    const float* W2 = (const float*)d_in[4];
    const float* b2 = (const float*)d_in[5];
    const float* Wp = (const float*)d_in[6];
    const float* bp = (const float*)d_in[7];
    float* out = (float*)d_out;

    const int nnz    = in_sizes[1] / 2;    // 800000
    const int nNodes = in_sizes[0] / 256;  // 50000
    const int nEdges = 50000;              // N_EDGES (not derivable from inputs)

    char* w = (char*)d_ws;
    const size_t SEG = 200192;             // >= 50048*4, 256B aligned
    int*   deg_e  = (int*)(w + 0 * SEG);
    int*   deg_n  = (int*)(w + 1 * SEG);
    int*   offs_e = (int*)(w + 2 * SEG);
    int*   offs_n = (int*)(w + 3 * SEG);
    float* binv   = (float*)(w + 4 * SEG);
    float* dinv   = (float*)(w + 5 * SEG);
    int*   curEb  = (int*)(w + 6 * SEG + 256);    // 391 ints
    int*   curNb  = (int*)(w + 6 * SEG + 2304);   // 391 ints
    int*   baseE  = (int*)(w + 6 * SEG + 4352);   // 392 ints
    int*   baseN  = (int*)(w + 6 * SEG + 6400);   // 392 ints
    char* p = w + 6 * SEG + 8448;
    u16* adj_e = (u16*)p;  p += (size_t)nnz * 2;              // 1.6 MB
    u16* adj_n = (u16*)p;  p += (size_t)nnz * 2;              // 1.6 MB
    f16* h0  = (f16*)p;                                       // 4 planes x 50000 x 32 f16
    f16* m1  = (f16*)(p + (size_t)nNodes * 128 * 2);          // 4 planes x 50000 x 32 f16
    f16* h1w = h0;                                            // reuse: 2 planes x 50000 x 32
    f16* m2  = (f16*)((char*)h0 + (size_t)nNodes * 64 * 2);   // disjoint from h1w
    // pre-split weight images after m1 region
    u16* w1sp = (u16*)(p + 2 * (size_t)nNodes * 128 * 2);     // 4 chunks * 18432 u16
    u16* w2sp = w1sp + 4 * 18432;                             // 2 chunks * 9216 u16
    u16* wpsp = w2sp + 2 * 9216;                              // 1 chunk  * 9216 u16

    const int nbE = (nEdges + 127) >> 7;             // 391
    const int nbN = (nNodes + 127) >> 7;             // 391
    // tmp bucket regions alias m1 (dead until gather1 writes it, after bin_build)
    u32* tmpE = (u32*)m1;
    u32* tmpN = tmpE + (size_t)nbE * BCAP;

    const size_t F1OFF = (size_t)nNodes * 64;        // out: z | f1 | f2 (f32)
    const size_t F2OFF = F1OFF + (size_t)nNodes * 128;

    hipMemsetAsync(w + 6 * SEG + 256, 0, 4096, stream);   // zero bucket cursors
    wsplit_all_kernel<<<(4*128*72 + 2*64*72 + 1*64*72 + 255) / 256, 256, 0, stream>>>(
        W1, W2, Wp, w1sp, w2sp, wpsp);
    bin_scatter_kernel<<<(nnz + 4095) / 4096, 256, 0, stream>>>(
        hidx, curEb, curNb, tmpE, tmpN, nnz, nNodes, nEdges);
    bkt_scan_kernel<<<2, 64, 0, stream>>>(curEb, curNb, baseE, baseN, nbE, nbN);
    bin_build_kernel<<<nbE + nbN, 256, 0, stream>>>(
        tmpE, tmpN, baseE, baseN,
        deg_e, offs_e, binv, adj_e,
        deg_n, offs_n, dinv, adj_n,
        nEdges, nNodes, nbE);

    const int chunksE = (nEdges + 63) / 64;          // 782
    const int chunksN = (nNodes + 63) / 64;          // 782

    // layer 1: h0 = x @ W1 (f16 planes SW=32, 4 planes)
    gemm_mfma_kernel<256, 128, false, 1><<<256, 1024, 0, stream>>>(x, w1sp, nullptr, h0, nNodes);
    gather_slice_kernel<4, false, 128><<<chunksE * 4, 256, 0, stream>>>(
        h0, adj_e, offs_e, deg_e, binv, nullptr, m1, nEdges, nNodes);
    gather_slice_kernel<4, true, 128><<<chunksN * 4, 256, 0, stream>>>(
        m1, adj_n, offs_n, deg_n, dinv, b1, out + F1OFF, nNodes, nEdges);

    // layer 2: h1w = f1 @ W2 (f16 planes SW=32, 2 planes)
    gemm_mfma_kernel<128, 64, false, 1><<<391, 1024, 0, stream>>>(
        out + F1OFF, w2sp, nullptr, h1w, nNodes);
    gather_slice_kernel<2, false, 64><<<chunksE * 2, 256, 0, stream>>>(
        h1w, adj_e, offs_e, deg_e, binv, nullptr, m2, nEdges, nNodes);
    gather_slice_kernel<2, true, 64><<<chunksN * 2, 256, 0, stream>>>(
        m2, adj_n, offs_n, deg_n, dinv, b2, out + F2OFF, nNodes, nEdges);

    // projection: z = f2 @ Wp + bp (f32 row-major)
    gemm_mfma_kernel<64, 64, true, 0><<<391, 1024, 0, stream>>>(
        out + F2OFF, wpsp, bp, out, nNodes);
}